// Round 8
// baseline (6323.666 us; speedup 1.0000x reference)
//
#include <hip/hip_runtime.h>
#include <hip/hip_bf16.h>

// LightGCN 3-hop propagation, 150k nodes, 4.8M edges, EMB=64.
// Round 8: hop rewritten as bucket-local LDS accumulation over COL-SORTED
// edge streams. R7 evidence: hop FETCH 589 MB = every gather LLC-served
// (prev 19.2MB >> 4MB/XCD L2 under random access). All 586 hop blocks are
// co-resident and walk cols in ascending order -> sliding col window stays
// L2-resident -> gather becomes mostly L2 hits.
//   build: detect -> init_vec -> bucket_hist -> bucket_scan -> bin (row-bucket
//          runs) -> col_sort (per-bucket, by col>>8; replaces local_fill/rowptr)
//   hops:  hop_lds x3 (64KB LDS acc, ds_add_f32, 2 blocks/CU)
// Keeps dtype-adaptive flag + atomic fallback + sentinel.

#define NUM_USERS 100000
#define NUM_ITEMS 50000
#define N_NODES   150000
#define EMB       64
#define N_EDGES   4800000
#define NODE_ELEMS (N_NODES * EMB)   // 9,600,000
#define U_ELEMS    (NUM_USERS * EMB) // 6,400,000
#define I_ELEMS    (NUM_ITEMS * EMB) // 3,200,000

#define RPB 256                           // rows per bucket
#define NB  ((N_NODES + RPB - 1) / RPB)   // 586 buckets
#define EPB 8192                          // edges staged per bin block

typedef __hip_bfloat16 bf16;

// flag bit0: float arrays are bf16 (else fp32). bit1: edge_index int64 (else int32).
__global__ void detect_kernel(const unsigned short* __restrict__ u16,
                              const int* __restrict__ ei32,
                              int* __restrict__ flag,
                              int* __restrict__ bucket_cnt)
{
    __shared__ int s_fp32, s_i32;
    if (threadIdx.x == 0) { s_fp32 = 0; s_i32 = 0; }
    __syncthreads();
    int t = threadIdx.x;
    for (int i = t; i < NB + 2; i += 256) bucket_cnt[i] = 0;
    unsigned short u = u16[t];
    int e = (u >> 7) & 0xFF;
    if (e >= 0xC0) atomicOr(&s_fp32, 1);
    if (t < 64 && ei32[2 * t + 1] != 0) atomicOr(&s_i32, 1);
    __syncthreads();
    if (t == 0) {
        int f = 0;
        if (!s_fp32) f |= 1;
        if (!s_i32)  f |= 2;
        *flag = f;
    }
}

__device__ __forceinline__ int load_row(const int* ei32, int f, size_t e) {
    return (f & 2) ? ei32[2 * e] : ei32[e];
}
__device__ __forceinline__ int load_col(const int* ei32, int f, size_t e) {
    return (f & 2) ? ei32[2 * ((size_t)N_EDGES + e)] : ei32[(size_t)N_EDGES + e];
}
__device__ __forceinline__ float load_w(const void* ew, int f, size_t e) {
    return (f & 1) ? __bfloat162float(((const bf16*)ew)[e]) : ((const float*)ew)[e];
}

// ---------- vectorized init: A + passthrough (ACC fused into hop1) ----------
__global__ void init_vec_kernel(const void* __restrict__ users,
                                const void* __restrict__ items,
                                void* __restrict__ out,
                                void* __restrict__ A,
                                const int* __restrict__ flag)
{
    int g = blockIdx.x * blockDim.x + threadIdx.x;   // NODE_ELEMS/4 threads
    if (g >= NODE_ELEMS / 4) return;
    int g4 = g * 4;
    const bool isb = ((*flag) & 1);
    if (isb) {
        uint2 v;
        if (g4 < U_ELEMS) {
            v = ((const uint2*)users)[g];
            ((uint2*)((bf16*)out + U_ELEMS))[g] = v;
        } else {
            int ii = g - U_ELEMS / 4;
            v = ((const uint2*)items)[ii];
            ((uint2*)((bf16*)out + 2 * (size_t)U_ELEMS + I_ELEMS))[ii] = v;
        }
        ((uint2*)A)[g] = v;            // A stored bf16
    } else {
        float4 v;
        if (g4 < U_ELEMS) {
            v = ((const float4*)users)[g];
            ((float4*)((float*)out + U_ELEMS))[g] = v;
        } else {
            int ii = g - U_ELEMS / 4;
            v = ((const float4*)items)[ii];
            ((float4*)((float*)out + 2 * (size_t)U_ELEMS + I_ELEMS))[ii] = v;
        }
        ((float4*)A)[g] = v;           // A stored fp32
    }
}

// ---------- binned build ----------

__global__ void bucket_hist_kernel(const int* __restrict__ ei32,
                                   int* __restrict__ bucket_cnt,
                                   const int* __restrict__ flag)
{
    __shared__ int h[NB];
    for (int i = threadIdx.x; i < NB; i += blockDim.x) h[i] = 0;
    __syncthreads();
    const int f = *flag;
    const size_t stride = (size_t)gridDim.x * blockDim.x;
    for (size_t e = (size_t)blockIdx.x * blockDim.x + threadIdx.x; e < N_EDGES; e += stride)
        atomicAdd(&h[load_row(ei32, f, e) >> 8], 1);
    __syncthreads();
    for (int i = threadIdx.x; i < NB; i += blockDim.x)
        if (h[i]) atomicAdd(&bucket_cnt[i], h[i]);
}

__global__ void bucket_scan_kernel(const int* __restrict__ bucket_cnt,
                                   int* __restrict__ bucket_base,
                                   int* __restrict__ bucket_off)
{
    __shared__ int ls[16];
    const int t = threadIdx.x;           // 1024 threads, NB <= 1024
    const int lane = t & 63, wv = t >> 6;
    int x = (t < NB) ? bucket_cnt[t] : 0;
    int v = x;
    #pragma unroll
    for (int d = 1; d < 64; d <<= 1) { int y = __shfl_up(v, d, 64); if (lane >= d) v += y; }
    if (lane == 63) ls[wv] = v;
    __syncthreads();
    if (wv == 0 && lane < 16) {
        int s = ls[lane];
        #pragma unroll
        for (int d = 1; d < 16; d <<= 1) { int y = __shfl_up(s, d, 64); if (lane >= d) s += y; }
        ls[lane] = s;
    }
    __syncthreads();
    int waveoff = wv ? ls[wv - 1] : 0;
    int excl = waveoff + v - x;
    if (t < NB) { bucket_base[t] = excl; bucket_off[t] = excl; }
    if (t == 0) bucket_base[NB] = ls[15];   // == N_EDGES
}

// stage 8192 edges in LDS, rank by row-bucket, write bucket-contiguous runs.
__global__ __launch_bounds__(1024) void bin_kernel(const int* __restrict__ ei32,
                                                   const void* __restrict__ ew,
                                                   int* __restrict__ bucket_off,
                                                   int2* __restrict__ rec,
                                                   const int* __restrict__ flag)
{
    __shared__ int2 stage[EPB];            // 64 KB
    __shared__ unsigned short bof[EPB];    // 16 KB
    __shared__ int hist[NB], excl0[NB], rank_[NB], gbase[NB];
    __shared__ int ls[16];
    const int t = threadIdx.x;
    const size_t base_e = (size_t)blockIdx.x * EPB;
    const int cnt = (int)(((base_e + EPB) <= N_EDGES) ? EPB : (N_EDGES - base_e));
    for (int i = t; i < NB; i += 1024) hist[i] = 0;
    __syncthreads();
    const int f = *flag;
    int  mybkt[8];
    int2 myrec[8];
    #pragma unroll
    for (int k = 0; k < 8; ++k) {
        int idx = k * 1024 + t;
        if (idx < cnt) {
            size_t e = base_e + idx;
            int row = load_row(ei32, f, e);
            int col = load_col(ei32, f, e);
            float w = load_w(ew, f, e);
            mybkt[k] = row >> 8;
            myrec[k] = make_int2(col | ((row & 255) << 18), __float_as_int(w));
            atomicAdd(&hist[mybkt[k]], 1);
        } else mybkt[k] = -1;
    }
    __syncthreads();
    {   // scan hist -> excl0, rank_
        const int lane = t & 63, wv = t >> 6;
        int x = (t < NB) ? hist[t] : 0;
        int v = x;
        #pragma unroll
        for (int d = 1; d < 64; d <<= 1) { int y = __shfl_up(v, d, 64); if (lane >= d) v += y; }
        if (lane == 63) ls[wv] = v;
        __syncthreads();
        if (wv == 0 && lane < 16) {
            int s = ls[lane];
            #pragma unroll
            for (int d = 1; d < 16; d <<= 1) { int y = __shfl_up(s, d, 64); if (lane >= d) s += y; }
            ls[lane] = s;
        }
        __syncthreads();
        int waveoff = wv ? ls[wv - 1] : 0;
        int excl = waveoff + v - x;
        if (t < NB) { excl0[t] = excl; rank_[t] = excl; }
    }
    __syncthreads();
    if (t < NB && hist[t] > 0) gbase[t] = atomicAdd(&bucket_off[t], hist[t]);
    else if (t < NB)           gbase[t] = 0;
    #pragma unroll
    for (int k = 0; k < 8; ++k) {
        if (mybkt[k] >= 0) {
            int p = atomicAdd(&rank_[mybkt[k]], 1);
            stage[p] = myrec[k];
            bof[p]   = (unsigned short)mybkt[k];
        }
    }
    __syncthreads();
    for (int s = t; s < cnt; s += 1024) {
        int b = bof[s];
        rec[gbase[b] + (s - excl0[b])] = stage[s];   // coalesced runs per bucket
    }
}

// per-bucket sort by col-bucket (col>>8) -> rec2. Replaces local_fill/rowptr.
// Scatter confined to the bucket's ~64KB window (L2-local).
__global__ __launch_bounds__(1024) void col_sort_kernel(const int* __restrict__ bucket_base,
                                                        const int2* __restrict__ rec,
                                                        int2* __restrict__ rec2)
{
    __shared__ int hist[NB], off[NB], ls[16];
    const int b = blockIdx.x, t = threadIdx.x;
    const int lo = bucket_base[b], hi = bucket_base[b + 1];
    for (int i = t; i < NB; i += 1024) hist[i] = 0;
    __syncthreads();
    for (int s = lo + t; s < hi; s += 1024)
        atomicAdd(&hist[(rec[s].x & 0x3FFFF) >> 8], 1);
    __syncthreads();
    const int lane = t & 63, wv = t >> 6;
    int x = (t < NB) ? hist[t] : 0;
    int v = x;
    #pragma unroll
    for (int d = 1; d < 64; d <<= 1) { int y = __shfl_up(v, d, 64); if (lane >= d) v += y; }
    if (lane == 63) ls[wv] = v;
    __syncthreads();
    if (wv == 0 && lane < 16) {
        int s = ls[lane];
        #pragma unroll
        for (int d = 1; d < 16; d <<= 1) { int y = __shfl_up(s, d, 64); if (lane >= d) s += y; }
        ls[lane] = s;
    }
    __syncthreads();
    int waveoff = wv ? ls[wv - 1] : 0;
    if (t < NB) off[t] = lo + waveoff + v - x;
    __syncthreads();
    for (int s = lo + t; s < hi; s += 1024) {
        int2 r = rec[s];
        int cb = (r.x & 0x3FFFF) >> 8;
        int pos = atomicAdd(&off[cb], 1);
        rec2[pos] = r;
    }
}

// ---------- hop: one block per row-bucket, 64KB LDS fp32 accumulator ----------
// Edges are col-sorted; all 586 blocks co-resident walk cols in the same
// ascending order -> gather window stays L2-resident.
// FIRST: acc = emb0 + a. LAST: out = (acc + a)/4.

template <bool FIRST, bool LAST>
__global__ __launch_bounds__(1024) void hop_lds_kernel(const int* __restrict__ bucket_base,
                                                       const int2* __restrict__ rec2,
                                                       const void* __restrict__ prev,
                                                       void* __restrict__ next,
                                                       float* __restrict__ acc,
                                                       void* __restrict__ out,
                                                       const int* __restrict__ flag)
{
    __shared__ float accl[RPB * EMB];     // 64 KB
    const int b = blockIdx.x, t = threadIdx.x;
    const int lo = bucket_base[b], hi = bucket_base[b + 1];
    const int row0 = b * RPB;
    const int rows = (N_NODES - row0 < RPB) ? (N_NODES - row0) : RPB;
    for (int i = t; i < RPB * EMB; i += 1024) accl[i] = 0.0f;
    __syncthreads();
    const bool isb = ((*flag) & 1);
    const int wid = t >> 6, lane = t & 63;
    const int nvalid = hi - lo;
    if (isb) {
        const bf16* p = (const bf16*)prev;
        for (int c = wid; 4 * c < nvalid; c += 16) {     // wave takes 4-edge chunks
            int s = lo + 4 * c;
            int2 r0 = rec2[s];
            int2 r1 = (s + 1 < hi) ? rec2[s + 1] : make_int2(0, 0);  // w=0 pad
            int2 r2 = (s + 2 < hi) ? rec2[s + 2] : make_int2(0, 0);
            int2 r3 = (s + 3 < hi) ? rec2[s + 3] : make_int2(0, 0);
            float v0 = __bfloat162float(p[(size_t)(r0.x & 0x3FFFF) * EMB + lane]);
            float v1 = __bfloat162float(p[(size_t)(r1.x & 0x3FFFF) * EMB + lane]);
            float v2 = __bfloat162float(p[(size_t)(r2.x & 0x3FFFF) * EMB + lane]);
            float v3 = __bfloat162float(p[(size_t)(r3.x & 0x3FFFF) * EMB + lane]);
            atomicAdd(&accl[((r0.x >> 18) << 6) + lane], __int_as_float(r0.y) * v0);
            atomicAdd(&accl[((r1.x >> 18) << 6) + lane], __int_as_float(r1.y) * v1);
            atomicAdd(&accl[((r2.x >> 18) << 6) + lane], __int_as_float(r2.y) * v2);
            atomicAdd(&accl[((r3.x >> 18) << 6) + lane], __int_as_float(r3.y) * v3);
        }
    } else {
        const float* p = (const float*)prev;
        for (int c = wid; 4 * c < nvalid; c += 16) {
            int s = lo + 4 * c;
            int2 r0 = rec2[s];
            int2 r1 = (s + 1 < hi) ? rec2[s + 1] : make_int2(0, 0);
            int2 r2 = (s + 2 < hi) ? rec2[s + 2] : make_int2(0, 0);
            int2 r3 = (s + 3 < hi) ? rec2[s + 3] : make_int2(0, 0);
            float v0 = p[(size_t)(r0.x & 0x3FFFF) * EMB + lane];
            float v1 = p[(size_t)(r1.x & 0x3FFFF) * EMB + lane];
            float v2 = p[(size_t)(r2.x & 0x3FFFF) * EMB + lane];
            float v3 = p[(size_t)(r3.x & 0x3FFFF) * EMB + lane];
            atomicAdd(&accl[((r0.x >> 18) << 6) + lane], __int_as_float(r0.y) * v0);
            atomicAdd(&accl[((r1.x >> 18) << 6) + lane], __int_as_float(r1.y) * v1);
            atomicAdd(&accl[((r2.x >> 18) << 6) + lane], __int_as_float(r2.y) * v2);
            atomicAdd(&accl[((r3.x >> 18) << 6) + lane], __int_as_float(r3.y) * v3);
        }
    }
    __syncthreads();
    for (int i = t; i < rows * EMB; i += 1024) {
        int rl = i >> 6, ln = i & 63;
        size_t o = (size_t)(row0 + rl) * EMB + ln;
        float a = accl[i];
        if (LAST) {
            float vv = (acc[o] + a) * 0.25f;
            size_t oo = (row0 + rl < NUM_USERS) ? o : o + (size_t)U_ELEMS;
            if (isb) ((bf16*)out)[oo]  = __float2bfloat16(vv);
            else     ((float*)out)[oo] = vv;
        } else {
            if (isb) ((bf16*)next)[o] = __float2bfloat16(a);
            else     ((float*)next)[o] = a;
            if (FIRST) {
                float e0 = isb ? __bfloat162float(((const bf16*)prev)[o])
                               : ((const float*)prev)[o];
                acc[o] = e0 + a;
            } else {
                acc[o] += a;
            }
        }
    }
}

// ---------- atomic fallback (R3) ----------

__global__ void init_kernel(const void* __restrict__ users,
                            const void* __restrict__ items,
                            void* __restrict__ out,
                            float* __restrict__ A,
                            float* __restrict__ B,
                            float* __restrict__ ACC,
                            const int* __restrict__ flag)
{
    int gid = blockIdx.x * blockDim.x + threadIdx.x;
    if (gid >= NODE_ELEMS) return;
    const bool isb = ((*flag) & 1);
    float v;
    if (gid < U_ELEMS) {
        if (isb) { bf16 b = ((const bf16*)users)[gid]; v = __bfloat162float(b); ((bf16*)out)[U_ELEMS + gid] = b; }
        else     { float fv = ((const float*)users)[gid]; v = fv; ((float*)out)[U_ELEMS + gid] = fv; }
    } else {
        int ii = gid - U_ELEMS;
        if (isb) { bf16 b = ((const bf16*)items)[ii]; v = __bfloat162float(b); ((bf16*)out)[2 * U_ELEMS + I_ELEMS + ii] = b; }
        else     { float fv = ((const float*)items)[ii]; v = fv; ((float*)out)[2 * U_ELEMS + I_ELEMS + ii] = fv; }
    }
    A[gid]   = v;
    B[gid]   = 0.0f;
    ACC[gid] = v;
}

__global__ void finalize_kernel(const float* __restrict__ acc,
                                void* __restrict__ out,
                                const int* __restrict__ flag)
{
    int gid = blockIdx.x * blockDim.x + threadIdx.x;
    if (gid >= NODE_ELEMS) return;
    const bool isb = ((*flag) & 1);
    float v = acc[gid] * 0.25f;
    size_t o = (gid < U_ELEMS) ? (size_t)gid : (size_t)(2 * U_ELEMS + (gid - U_ELEMS));
    if (isb) ((bf16*)out)[o]  = __float2bfloat16(v);
    else     ((float*)out)[o] = v;
}

__global__ void scatter_kernel(const int* __restrict__ ei32,
                               const void* __restrict__ ew,
                               const float* __restrict__ prev,
                               float* __restrict__ next,
                               const int* __restrict__ flag)
{
    int gid = blockIdx.x * blockDim.x + threadIdx.x;
    if (gid >= N_EDGES * 16) return;
    const int f = *flag;
    int e = gid >> 4;
    int j = (gid & 15) << 2;
    int row = load_row(ei32, f, e);
    int col = load_col(ei32, f, e);
    float w = load_w(ew, f, e);
    const float4 v = *reinterpret_cast<const float4*>(prev + (size_t)col * EMB + j);
    float* dst = next + (size_t)row * EMB + j;
    unsafeAtomicAdd(dst + 0, w * v.x);
    unsafeAtomicAdd(dst + 1, w * v.y);
    unsafeAtomicAdd(dst + 2, w * v.z);
    unsafeAtomicAdd(dst + 3, w * v.w);
}

__global__ void accum_zero_kernel(float* __restrict__ acc,
                                  const float* __restrict__ next,
                                  float* __restrict__ prevz)
{
    int gid = blockIdx.x * blockDim.x + threadIdx.x;
    if (gid >= NODE_ELEMS) return;
    acc[gid] += next[gid];
    prevz[gid] = 0.0f;
}

__global__ void sentinel_kernel(unsigned int* __restrict__ out, int nwords)
{
    int gid = blockIdx.x * blockDim.x + threadIdx.x;
    if (gid < nwords) out[gid] = 0x447A447Au;
}

extern "C" void kernel_launch(void* const* d_in, const int* in_sizes, int n_in,
                              void* d_out, int out_size, void* d_ws, size_t ws_size,
                              hipStream_t stream)
{
    const void* users = d_in[0];
    const void* items = d_in[1];
    const int*  ei32  = (const int*)d_in[2];
    const void* ew    = d_in[3];

    char* wsb  = (char*)d_ws;
    int*  flag = (int*)wsb;
    float* A   = (float*)(wsb + 256);              // fp32-sized; holds bf16 in CSR path
    float* B   = A + (size_t)NODE_ELEMS;           // hop ping buffer; aliases rec
    float* ACC = B + (size_t)NODE_ELEMS;
    char* p    = (char*)(ACC + (size_t)NODE_ELEMS);
    int2* rec2        = (int2*)p; p += (size_t)N_EDGES * sizeof(int2);   // 38.4 MB
    int*  bucket_cnt  = (int*)p;  p += (NB + 2) * sizeof(int);
    int*  bucket_base = (int*)p;  p += (NB + 2) * sizeof(int);
    int*  bucket_off  = (int*)p;  p += (NB + 2) * sizeof(int);
    int2* rec         = (int2*)B;                  // alias: dead before hop1 writes B

    const size_t need_full   = (size_t)(p - wsb);                  // ~153.6 MB
    const size_t need_atomic = 256 + 3 * (size_t)NODE_ELEMS * sizeof(float);
    const int BLK = 256;
    const int node_blocks = (NODE_ELEMS + BLK - 1) / BLK;
    const int vec_blocks  = (NODE_ELEMS / 4 + BLK - 1) / BLK;
    const int bin_blocks  = (N_EDGES + EPB - 1) / EPB;   // 586

    if (ws_size >= need_full) {
        detect_kernel<<<1, BLK, 0, stream>>>((const unsigned short*)users, ei32, flag, bucket_cnt);
        init_vec_kernel<<<vec_blocks, BLK, 0, stream>>>(users, items, d_out, A, flag);
        bucket_hist_kernel<<<1024, BLK, 0, stream>>>(ei32, bucket_cnt, flag);
        bucket_scan_kernel<<<1, 1024, 0, stream>>>(bucket_cnt, bucket_base, bucket_off);
        bin_kernel<<<bin_blocks, 1024, 0, stream>>>(ei32, ew, bucket_off, rec, flag);
        col_sort_kernel<<<NB, 1024, 0, stream>>>(bucket_base, rec, rec2);

        hop_lds_kernel<true,  false><<<NB, 1024, 0, stream>>>(bucket_base, rec2, A, B, ACC, d_out, flag);
        hop_lds_kernel<false, false><<<NB, 1024, 0, stream>>>(bucket_base, rec2, B, A, ACC, d_out, flag);
        hop_lds_kernel<false, true ><<<NB, 1024, 0, stream>>>(bucket_base, rec2, A, B, ACC, d_out, flag);
    } else if (ws_size >= need_atomic) {
        const int sedge_blocks = (N_EDGES * 16 + BLK - 1) / BLK;
        detect_kernel<<<1, BLK, 0, stream>>>((const unsigned short*)users, ei32, flag, bucket_cnt);
        init_kernel<<<node_blocks, BLK, 0, stream>>>(users, items, d_out, A, B, ACC, flag);
        float* prev = A;
        float* nxt  = B;
        for (int h = 0; h < 3; ++h) {
            scatter_kernel<<<sedge_blocks, BLK, 0, stream>>>(ei32, ew, prev, nxt, flag);
            accum_zero_kernel<<<node_blocks, BLK, 0, stream>>>(ACC, nxt, prev);
            float* t = prev; prev = nxt; nxt = t;
        }
        finalize_kernel<<<node_blocks, BLK, 0, stream>>>(ACC, d_out, flag);
    } else {
        int nwords = out_size / 2;
        sentinel_kernel<<<(nwords + BLK - 1) / BLK, BLK, 0, stream>>>((unsigned int*)d_out, nwords);
    }
}